// Round 4
// baseline (289.241 us; speedup 1.0000x reference)
//
#include <hip/hip_runtime.h>
#include <hip/hip_bf16.h>

#define N_NODES 1048576
#define H 128
#define B_SESS 4096
#define TILE 128
#define NBLOCKS 256
#define TILES_PER_BLOCK (N_NODES / TILE / NBLOCKS)   // 32

typedef __attribute__((ext_vector_type(8))) short bf16x8;
typedef __attribute__((ext_vector_type(4))) short bf16x4;
typedef __attribute__((ext_vector_type(4))) float f32x4;

__device__ inline unsigned short f2bf(float f) {
  unsigned int u = __float_as_uint(f);
  u += 0x7FFFu + ((u >> 16) & 1u);   // round-to-nearest-even
  return (unsigned short)(u >> 16);
}

// swizzled linear index for a [rows][128] bf16 tile: 16B units XOR'd by row&7
__device__ inline int swz(int r, int c) {
  return r * 128 + (((c >> 3) ^ (r & 7)) << 3) + (c & 7);
}

// ---------------------------------------------------------------- kernel 0
// one-shot W2 f32 -> bf16, stored PRE-SWIZZLED (matches k_main's LDS layout)
__global__ void k_w2(const float* __restrict__ W2, unsigned short* __restrict__ W2s) {
  int i = blockIdx.x * 256 + threadIdx.x;   // 2048 threads x 8 elems
  int r = i >> 4, u = i & 15;
  const float* src = W2 + (size_t)r * 128 + u * 8;
  float4 a = *reinterpret_cast<const float4*>(src);
  float4 b = *reinterpret_cast<const float4*>(src + 4);
  bf16x8 o;
  o[0] = (short)f2bf(a.x); o[1] = (short)f2bf(a.y);
  o[2] = (short)f2bf(a.z); o[3] = (short)f2bf(a.w);
  o[4] = (short)f2bf(b.x); o[5] = (short)f2bf(b.y);
  o[6] = (short)f2bf(b.z); o[7] = (short)f2bf(b.w);
  *reinterpret_cast<bf16x8*>(W2s + r * 128 + (((u ^ (r & 7))) << 3)) = o;
}

// ---------------------------------------------------------------- kernel 1
__global__ void k_last(const int* __restrict__ batch, int* __restrict__ last_idx) {
  int i = blockIdx.x * blockDim.x + threadIdx.x;
  if (i < N_NODES) {
    if (i == N_NODES - 1 || batch[i] != batch[i + 1]) last_idx[batch[i]] = i;
  }
}

// ---------------------------------------------------------------- kernel 2
// A_pre[b,h] = v_n[b] . W1[h,:] + b1[h] + b2[h]
__global__ void k_apre(const float* __restrict__ x, const int* __restrict__ last_idx,
                       const float* __restrict__ W1, const float* __restrict__ b1,
                       const float* __restrict__ b2, float* __restrict__ A_pre) {
  __shared__ float Wl[128][132];
  __shared__ float vn[8][128];
  int t = threadIdx.x;
  for (int i = 0; i < 16; ++i) {
    int e = (t + i * 256) * 4;
    int r = e >> 7, c = e & 127;
    float4 v = *reinterpret_cast<const float4*>(W1 + e);
    Wl[r][c] = v.x; Wl[r][c + 1] = v.y; Wl[r][c + 2] = v.z; Wl[r][c + 3] = v.w;
  }
  int b0 = blockIdx.x * 8;
  for (int i = t; i < 8 * 128; i += 256) {
    int s = i >> 7, c = i & 127;
    vn[s][c] = x[(size_t)last_idx[b0 + s] * H + c];
  }
  __syncthreads();
  int h = t & 127, si = t >> 7;
  float bias = b1[h] + b2[h];
  for (int s = si; s < 8; s += 2) {
    float acc = bias;
    #pragma unroll
    for (int k = 0; k < 128; k += 4) {
      float4 w = *reinterpret_cast<const float4*>(&Wl[h][k]);
      acc += vn[s][k] * w.x + vn[s][k + 1] * w.y + vn[s][k + 2] * w.z + vn[s][k + 3] * w.w;
    }
    A_pre[(size_t)(b0 + s) * H + h] = acc;
  }
}

// ---------------------------------------------------------------- kernel 3
// Persistent fused kernel: per 128-node tile
//   z = A_pre[batch] + x@W2^T (bf16 MFMA), alpha = sigmoid(z).Wq + bq,
//   s_g[b] += alpha * x    — double-buffered x tile, issue-early/write-late.
__launch_bounds__(512)
__global__ void k_main(const float* __restrict__ x, const int* __restrict__ batch,
                       const unsigned short* __restrict__ W2s, const float* __restrict__ Wq,
                       const float* __restrict__ bq, const float* __restrict__ A_pre,
                       float* __restrict__ s_g) {
  __shared__ unsigned short Wl[128 * 128];       // swizzled bf16 W2 (32 KB)
  __shared__ unsigned short Xl[2][TILE * 128];   // swizzled bf16 x tiles (2x32 KB)
  __shared__ float alph[TILE];
  __shared__ int bseg[2][TILE + 1];
  __shared__ float wq[128];

  int t = threadIdx.x;
  // stage pre-swizzled W2 once (linear 16B copies)
  #pragma unroll
  for (int i = 0; i < 4; ++i) {
    int e = (t + i * 512) * 8;
    *reinterpret_cast<bf16x8*>(&Wl[e]) = *reinterpret_cast<const bf16x8*>(W2s + e);
  }
  if (t < 128) wq[t] = Wq[t];
  float bqv = bq[0];

  int tile0 = blockIdx.x * TILES_PER_BLOCK;
  int w = t >> 6, lane = t & 63, r = lane & 15, ks = lane >> 4;
  int arow = w * 16 + r;

  // ---- prologue: stage tile 0 into buffer 0
  {
    size_t base = (size_t)tile0 * TILE * H;
    float4 h4[8];
    #pragma unroll
    for (int i = 0; i < 8; ++i)
      h4[i] = *reinterpret_cast<const float4*>(x + base + (size_t)(i * 512 + t) * 4);
    int bv = 0;
    if (t <= TILE) {
      int idx = tile0 * TILE + t;
      bv = (idx < N_NODES) ? batch[idx] : -1;
    }
    #pragma unroll
    for (int i = 0; i < 8; ++i) {
      int e = (i * 512 + t) * 4;
      int rr = e >> 7, c = e & 127;
      bf16x4 o;
      o[0] = (short)f2bf(h4[i].x); o[1] = (short)f2bf(h4[i].y);
      o[2] = (short)f2bf(h4[i].z); o[3] = (short)f2bf(h4[i].w);
      *reinterpret_cast<bf16x4*>(&Xl[0][swz(rr, c)]) = o;
    }
    if (t <= TILE) bseg[0][t] = bv;
  }
  __syncthreads();

  // ---- main loop over tiles
  for (int it = 0; it < TILES_PER_BLOCK; ++it) {
    int cur = it & 1, nxt = cur ^ 1;
    int node0 = (tile0 + it) * TILE;

    // issue-early: next tile's loads held in registers
    float4 h4[8];
    int bv = 0;
    bool pre = (it + 1 < TILES_PER_BLOCK);
    if (pre) {
      size_t base = (size_t)(node0 + TILE) * H;
      #pragma unroll
      for (int i = 0; i < 8; ++i)
        h4[i] = *reinterpret_cast<const float4*>(x + base + (size_t)(i * 512 + t) * 4);
      if (t <= TILE) {
        int idx = node0 + TILE + t;
        bv = (idx < N_NODES) ? batch[idx] : -1;
      }
    }

    // ---- phase 1: MFMA z-tiles + alpha
    f32x4 acc[8];
    #pragma unroll
    for (int nt = 0; nt < 8; ++nt) acc[nt] = (f32x4){0.f, 0.f, 0.f, 0.f};
    #pragma unroll
    for (int k0 = 0; k0 < 128; k0 += 32) {
      int u = (k0 >> 3) + ks;
      bf16x8 a = *reinterpret_cast<const bf16x8*>(&Xl[cur][arow * 128 + ((u ^ (arow & 7)) << 3)]);
      #pragma unroll
      for (int nt = 0; nt < 8; ++nt) {
        bf16x8 b = *reinterpret_cast<const bf16x8*>(&Wl[(nt * 16 + r) * 128 + ((u ^ (r & 7)) << 3)]);
        acc[nt] = __builtin_amdgcn_mfma_f32_16x16x32_bf16(a, b, acc[nt], 0, 0, 0);
      }
    }
    #pragma unroll
    for (int j = 0; j < 4; ++j) {
      int lrow = w * 16 + ks * 4 + j;
      const float* ap = A_pre + (size_t)bseg[cur][lrow] * H;
      float pa = 0.f;
      #pragma unroll
      for (int nt = 0; nt < 8; ++nt) {
        float z = acc[nt][j] + ap[nt * 16 + r];
        float g = 1.0f / (1.0f + __expf(-z));
        pa += g * wq[nt * 16 + r];
      }
      pa += __shfl_xor(pa, 1);
      pa += __shfl_xor(pa, 2);
      pa += __shfl_xor(pa, 4);
      pa += __shfl_xor(pa, 8);
      if (r == 0) alph[lrow] = pa + bqv;
    }
    __syncthreads();

    // ---- phase 2: s_g[b,h] += alpha_i * x[i,h]  (x from LDS bf16)
    {
      int h = t & 127, grp = t >> 7;
      int base = grp * 32;
      int hu = h >> 3, hl = h & 7;
      float accum = 0.f;
      #pragma unroll 8
      for (int n = 0; n < 32; ++n) {
        int ln = base + n;
        unsigned short xs = Xl[cur][ln * 128 + (((hu ^ (ln & 7))) << 3) + hl];
        float xv = __uint_as_float((unsigned int)xs << 16);
        accum += alph[ln] * xv;
        if (bseg[cur][ln] != bseg[cur][ln + 1]) {
          atomicAdd(&s_g[(size_t)bseg[cur][ln] * H + h], accum);
          accum = 0.f;
        }
      }
      if (accum != 0.f) atomicAdd(&s_g[(size_t)bseg[cur][base + 31] * H + h], accum);
    }

    // ---- write-late: convert held registers into next buffer
    if (pre) {
      #pragma unroll
      for (int i = 0; i < 8; ++i) {
        int e = (i * 512 + t) * 4;
        int rr = e >> 7, c = e & 127;
        bf16x4 o;
        o[0] = (short)f2bf(h4[i].x); o[1] = (short)f2bf(h4[i].y);
        o[2] = (short)f2bf(h4[i].z); o[3] = (short)f2bf(h4[i].w);
        *reinterpret_cast<bf16x4*>(&Xl[nxt][swz(rr, c)]) = o;
      }
      if (t <= TILE) bseg[nxt][t] = bv;
    }
    __syncthreads();
  }
}

// ---------------------------------------------------------------- kernel 4
// s_h[b,h] = b3[h] + concat(v_n[b], s_g[b]) . W3[h,:]
__global__ void k_final(const float* __restrict__ x, const int* __restrict__ last_idx,
                        const float* __restrict__ s_g, const float* __restrict__ W3,
                        const float* __restrict__ b3, float* __restrict__ out) {
  __shared__ float Wl[128][132];
  __shared__ float vin[8][256];
  int t = threadIdx.x;
  int b0 = blockIdx.x * 8;
  for (int i = t; i < 8 * 256; i += 256) {
    int s = i >> 8, c = i & 255;
    float v;
    if (c < 128) v = x[(size_t)last_idx[b0 + s] * H + c];
    else         v = s_g[(size_t)(b0 + s) * H + (c - 128)];
    vin[s][c] = v;
  }
  int h = t & 127, si = t >> 7;
  float res[4];
  for (int half = 0; half < 2; ++half) {
    __syncthreads();
    for (int i = 0; i < 16; ++i) {
      int e = (t + i * 256) * 4;
      int r = e >> 7, c = e & 127;
      float4 v = *reinterpret_cast<const float4*>(W3 + (size_t)r * 256 + half * 128 + c);
      Wl[r][c] = v.x; Wl[r][c + 1] = v.y; Wl[r][c + 2] = v.z; Wl[r][c + 3] = v.w;
    }
    __syncthreads();
    #pragma unroll
    for (int sI = 0; sI < 4; ++sI) {
      int s = si + sI * 2;
      float acc = 0.f;
      #pragma unroll
      for (int k = 0; k < 128; k += 4) {
        float4 wv = *reinterpret_cast<const float4*>(&Wl[h][k]);
        acc += vin[s][half * 128 + k] * wv.x + vin[s][half * 128 + k + 1] * wv.y +
               vin[s][half * 128 + k + 2] * wv.z + vin[s][half * 128 + k + 3] * wv.w;
      }
      if (half == 0) res[sI] = acc;
      else out[(size_t)(b0 + s) * H + h] = res[sI] + acc + b3[h];
    }
  }
}

// ----------------------------------------------------------------
extern "C" void kernel_launch(void* const* d_in, const int* in_sizes, int n_in,
                              void* d_out, int out_size, void* d_ws, size_t ws_size,
                              hipStream_t stream) {
  const float* x     = (const float*)d_in[0];
  const int*   batch = (const int*)d_in[1];
  const float* W1    = (const float*)d_in[2];
  const float* b1    = (const float*)d_in[3];
  const float* W2    = (const float*)d_in[4];
  const float* b2    = (const float*)d_in[5];
  const float* Wq    = (const float*)d_in[6];
  const float* bq    = (const float*)d_in[7];
  const float* W3    = (const float*)d_in[8];
  const float* b3    = (const float*)d_in[9];
  float* out = (float*)d_out;

  char* ws = (char*)d_ws;
  int*            last_idx = (int*)ws;                                    // 16 KB
  float*          A_pre    = (float*)(ws + 16384);                        // 2 MB
  float*          s_g      = (float*)(ws + 16384 + 2097152);              // 2 MB
  unsigned short* W2s      = (unsigned short*)(ws + 16384 + 2 * 2097152); // 32 KB

  hipMemsetAsync(s_g, 0, (size_t)B_SESS * H * sizeof(float), stream);
  k_w2<<<8, 256, 0, stream>>>(W2, W2s);
  k_last<<<N_NODES / 256, 256, 0, stream>>>(batch, last_idx);
  k_apre<<<B_SESS / 8, 256, 0, stream>>>(x, last_idx, W1, b1, b2, A_pre);
  k_main<<<NBLOCKS, 512, 0, stream>>>(x, batch, W2s, Wq, bq, A_pre, s_g);
  k_final<<<B_SESS / 8, 256, 0, stream>>>(x, last_idx, s_g, W3, b3, out);
}

// Round 5
// 236.405 us; speedup vs baseline: 1.2235x; 1.2235x over previous
//
#include <hip/hip_runtime.h>
#include <hip/hip_bf16.h>

#define N_NODES 1048576
#define H 128
#define B_SESS 4096
#define TILE 64

typedef __attribute__((ext_vector_type(8))) short bf16x8;
typedef __attribute__((ext_vector_type(4))) short bf16x4;
typedef __attribute__((ext_vector_type(4))) float f32x4;

__device__ inline short bc(float f) {
  return (short)__builtin_bit_cast(unsigned short, __float2bfloat16(f));
}

// ---------------------------------------------------------------- kernel 1
// fused prep: last-index scan + s_g zero + W2 f32->bf16
__global__ void k_prep(const int* __restrict__ batch, int* __restrict__ last_idx,
                       const float* __restrict__ W2, unsigned short* __restrict__ W2b,
                       float* __restrict__ s_g) {
  int i = blockIdx.x * 256 + threadIdx.x;
  if (i < N_NODES) {
    if (i == N_NODES - 1 || batch[i] != batch[i + 1]) last_idx[batch[i]] = i;
  }
  if (i < B_SESS * H) s_g[i] = 0.f;
  if (i < 4096) {                       // 16384 floats / 4
    float4 v = *reinterpret_cast<const float4*>(W2 + (size_t)i * 4);
    bf16x4 o;
    o[0] = bc(v.x); o[1] = bc(v.y); o[2] = bc(v.z); o[3] = bc(v.w);
    *reinterpret_cast<bf16x4*>(W2b + (size_t)i * 4) = o;
  }
}

// ---------------------------------------------------------------- kernel 2
// A_pre[b,h] = v_n[b] . W1[h,:] + b1[h] + b2[h]
__global__ void k_apre(const float* __restrict__ x, const int* __restrict__ last_idx,
                       const float* __restrict__ W1, const float* __restrict__ b1,
                       const float* __restrict__ b2, float* __restrict__ A_pre) {
  __shared__ float Wl[128][132];
  __shared__ float vn[8][128];
  int t = threadIdx.x;
  for (int i = 0; i < 16; ++i) {
    int e = (t + i * 256) * 4;
    int r = e >> 7, c = e & 127;
    float4 v = *reinterpret_cast<const float4*>(W1 + e);
    Wl[r][c] = v.x; Wl[r][c + 1] = v.y; Wl[r][c + 2] = v.z; Wl[r][c + 3] = v.w;
  }
  int b0 = blockIdx.x * 8;
  for (int i = t; i < 8 * 128; i += 256) {
    int s = i >> 7, c = i & 127;
    vn[s][c] = x[(size_t)last_idx[b0 + s] * H + c];
  }
  __syncthreads();
  int h = t & 127, si = t >> 7;
  float bias = b1[h] + b2[h];
  for (int s = si; s < 8; s += 2) {
    float acc = bias;
    #pragma unroll
    for (int k = 0; k < 128; k += 4) {
      float4 w = *reinterpret_cast<const float4*>(&Wl[h][k]);
      acc += vn[s][k] * w.x + vn[s][k + 1] * w.y + vn[s][k + 2] * w.z + vn[s][k + 3] * w.w;
    }
    A_pre[(size_t)(b0 + s) * H + h] = acc;
  }
}

// ---------------------------------------------------------------- kernel 3
// Fused: z = A_pre[batch] + x@W2^T (bf16 MFMA, A-frags direct from global,
// line-efficient paired loads), alpha = sigmoid(z).Wq + bq,
// s_g[b] += alpha * x (x re-read coalesced from L2).
// LDS = W2 tile only (~35.5 KB) -> 4 blocks/CU.
__global__ __launch_bounds__(256, 4)
void k_main(const float* __restrict__ x, const int* __restrict__ batch,
            const unsigned short* __restrict__ W2b, const float* __restrict__ Wq,
            const float* __restrict__ bq, const float* __restrict__ A_pre,
            float* __restrict__ s_g) {
  __shared__ unsigned short Wl[128][136];   // bf16 W2, pad-136 (2-way max on b128)
  __shared__ float alph[TILE];
  __shared__ int bseg[TILE + 1];
  int t = threadIdx.x;
  int node0 = blockIdx.x * TILE;
  int w = t >> 6, lane = t & 63, r = lane & 15, ks = lane >> 4;
  int myrow = w * 16 + r;

  // ---- A-fragment loads: paired float4 -> contiguous 32B per (k,lane).
  // Rows stride 512B; each 64B line fully consumed by the instruction pair.
  float4 af[8];
  const float* xrow = x + (size_t)(node0 + myrow) * H;
  #pragma unroll
  for (int k = 0; k < 4; ++k) {
    af[2 * k]     = *reinterpret_cast<const float4*>(xrow + k * 32 + ks * 8);
    af[2 * k + 1] = *reinterpret_cast<const float4*>(xrow + k * 32 + ks * 8 + 4);
  }
  // ---- stage W2 bf16 (32 KB): 256 threads x 8 x 16B, coalesced
  #pragma unroll
  for (int i = 0; i < 8; ++i) {
    int e = (t + i * 256) * 8;
    int rr = e >> 7, c = e & 127;
    *reinterpret_cast<bf16x8*>(&Wl[rr][c]) = *reinterpret_cast<const bf16x8*>(W2b + e);
  }
  if (t <= TILE) {
    int idx = node0 + t;
    bseg[t] = (idx < N_NODES) ? batch[idx] : -1;
  }
  __syncthreads();

  // ---- convert A-frags to bf16
  bf16x8 afr[4];
  #pragma unroll
  for (int k = 0; k < 4; ++k) {
    float4 lo = af[2 * k], hi = af[2 * k + 1];
    bf16x8 v;
    v[0] = bc(lo.x); v[1] = bc(lo.y); v[2] = bc(lo.z); v[3] = bc(lo.w);
    v[4] = bc(hi.x); v[5] = bc(hi.y); v[6] = bc(hi.z); v[7] = bc(hi.w);
    afr[k] = v;
  }

  // ---- phase 1: MFMA z-tiles
  f32x4 acc[8];
  #pragma unroll
  for (int nt = 0; nt < 8; ++nt) acc[nt] = (f32x4){0.f, 0.f, 0.f, 0.f};
  #pragma unroll
  for (int k = 0; k < 4; ++k) {
    #pragma unroll
    for (int nt = 0; nt < 8; ++nt) {
      bf16x8 b = *reinterpret_cast<const bf16x8*>(&Wl[nt * 16 + r][k * 32 + ks * 8]);
      acc[nt] = __builtin_amdgcn_mfma_f32_16x16x32_bf16(afr[k], b, acc[nt], 0, 0, 0);
    }
  }

  // ---- alpha: sigmoid + Wq-dot + 16-lane reduce
  float bqv = bq[0];
  float pa[4];
  #pragma unroll
  for (int j = 0; j < 4; ++j) {
    const float* ap = A_pre + (size_t)bseg[w * 16 + ks * 4 + j] * H;
    float s = 0.f;
    #pragma unroll
    for (int nt = 0; nt < 8; ++nt) {
      float z = acc[nt][j] + ap[nt * 16 + r];
      float g = 1.0f / (1.0f + __expf(-z));
      s += g * Wq[nt * 16 + r];
    }
    s += __shfl_xor(s, 1);
    s += __shfl_xor(s, 2);
    s += __shfl_xor(s, 4);
    s += __shfl_xor(s, 8);
    pa[j] = s + bqv;
  }
  if (r == 0) {
    #pragma unroll
    for (int j = 0; j < 4; ++j) alph[w * 16 + ks * 4 + j] = pa[j];
  }
  __syncthreads();

  // ---- phase 2: s_g[b,h] += alpha_i * x[i,h] (x coalesced from L2)
  int h = t & 127, grp = t >> 7;            // 2 groups x 32 nodes
  int base = grp * 32;
  const float* xp = x + (size_t)(node0 + base) * H + h;
  float xv[32];
  #pragma unroll
  for (int n = 0; n < 32; ++n) xv[n] = xp[(size_t)n * H];
  float accum = 0.f;
  #pragma unroll
  for (int n = 0; n < 32; ++n) {
    int ln = base + n;
    accum += alph[ln] * xv[n];
    if (bseg[ln] != bseg[ln + 1]) {
      atomicAdd(&s_g[(size_t)bseg[ln] * H + h], accum);
      accum = 0.f;
    }
  }
  if (accum != 0.f) atomicAdd(&s_g[(size_t)bseg[base + 31] * H + h], accum);
}

// ---------------------------------------------------------------- kernel 4
// s_h[b,h] = b3[h] + concat(v_n[b], s_g[b]) . W3[h,:]
__global__ void k_final(const float* __restrict__ x, const int* __restrict__ last_idx,
                        const float* __restrict__ s_g, const float* __restrict__ W3,
                        const float* __restrict__ b3, float* __restrict__ out) {
  __shared__ float Wl[128][132];
  __shared__ float vin[8][256];
  int t = threadIdx.x;
  int b0 = blockIdx.x * 8;
  for (int i = t; i < 8 * 256; i += 256) {
    int s = i >> 8, c = i & 255;
    float v;
    if (c < 128) v = x[(size_t)last_idx[b0 + s] * H + c];
    else         v = s_g[(size_t)(b0 + s) * H + (c - 128)];
    vin[s][c] = v;
  }
  int h = t & 127, si = t >> 7;
  float res[4];
  for (int half = 0; half < 2; ++half) {
    __syncthreads();
    for (int i = 0; i < 16; ++i) {
      int e = (t + i * 256) * 4;
      int r = e >> 7, c = e & 127;
      float4 v = *reinterpret_cast<const float4*>(W3 + (size_t)r * 256 + half * 128 + c);
      Wl[r][c] = v.x; Wl[r][c + 1] = v.y; Wl[r][c + 2] = v.z; Wl[r][c + 3] = v.w;
    }
    __syncthreads();
    #pragma unroll
    for (int sI = 0; sI < 4; ++sI) {
      int s = si + sI * 2;
      float acc = 0.f;
      #pragma unroll
      for (int k = 0; k < 128; k += 4) {
        float4 wv = *reinterpret_cast<const float4*>(&Wl[h][k]);
        acc += vin[s][half * 128 + k] * wv.x + vin[s][half * 128 + k + 1] * wv.y +
               vin[s][half * 128 + k + 2] * wv.z + vin[s][half * 128 + k + 3] * wv.w;
      }
      if (half == 0) res[sI] = acc;
      else out[(size_t)(b0 + s) * H + h] = res[sI] + acc + b3[h];
    }
  }
}

// ----------------------------------------------------------------
extern "C" void kernel_launch(void* const* d_in, const int* in_sizes, int n_in,
                              void* d_out, int out_size, void* d_ws, size_t ws_size,
                              hipStream_t stream) {
  const float* x     = (const float*)d_in[0];
  const int*   batch = (const int*)d_in[1];
  const float* W1    = (const float*)d_in[2];
  const float* b1    = (const float*)d_in[3];
  const float* W2    = (const float*)d_in[4];
  const float* b2    = (const float*)d_in[5];
  const float* Wq    = (const float*)d_in[6];
  const float* bq    = (const float*)d_in[7];
  const float* W3    = (const float*)d_in[8];
  const float* b3    = (const float*)d_in[9];
  float* out = (float*)d_out;

  char* ws = (char*)d_ws;
  int*            last_idx = (int*)ws;                                    // 16 KB
  float*          A_pre    = (float*)(ws + 16384);                        // 2 MB
  float*          s_g      = (float*)(ws + 16384 + 2097152);              // 2 MB
  unsigned short* W2b      = (unsigned short*)(ws + 16384 + 2 * 2097152); // 32 KB

  k_prep<<<N_NODES / 256, 256, 0, stream>>>(batch, last_idx, W2, W2b, s_g);
  k_apre<<<B_SESS / 8, 256, 0, stream>>>(x, last_idx, W1, b1, b2, A_pre);
  k_main<<<N_NODES / TILE, 256, 0, stream>>>(x, batch, W2b, Wq, bq, A_pre, s_g);
  k_final<<<B_SESS / 8, 256, 0, stream>>>(x, last_idx, s_g, W3, b3, out);
}

// Round 6
// 214.873 us; speedup vs baseline: 1.3461x; 1.1002x over previous
//
#include <hip/hip_runtime.h>
#include <hip/hip_bf16.h>

#define N_NODES 1048576
#define H 128
#define B_SESS 4096
#define TILE 64

typedef __attribute__((ext_vector_type(8))) short bf16x8;
typedef __attribute__((ext_vector_type(4))) short bf16x4;
typedef __attribute__((ext_vector_type(4))) float f32x4;

__device__ inline short bc(float f) {
  return (short)__builtin_bit_cast(unsigned short, __float2bfloat16(f));
}

// ---------------------------------------------------------------- kernel 1
// fused prep: last-index scan + s_g zero + W2 f32->bf16
__global__ void k_prep(const int* __restrict__ batch, int* __restrict__ last_idx,
                       const float* __restrict__ W2, unsigned short* __restrict__ W2b,
                       float* __restrict__ s_g) {
  int i = blockIdx.x * 256 + threadIdx.x;
  if (i < N_NODES) {
    if (i == N_NODES - 1 || batch[i] != batch[i + 1]) last_idx[batch[i]] = i;
  }
  if (i < B_SESS * H) s_g[i] = 0.f;
  if (i < 4096) {
    float4 v = *reinterpret_cast<const float4*>(W2 + (size_t)i * 4);
    bf16x4 o;
    o[0] = bc(v.x); o[1] = bc(v.y); o[2] = bc(v.z); o[3] = bc(v.w);
    *reinterpret_cast<bf16x4*>(W2b + (size_t)i * 4) = o;
  }
}

// ---------------------------------------------------------------- kernel 2
// A_pre[b,h] = v_n[b] . W1[h,:] + b1[h] + b2[h]
__global__ void k_apre(const float* __restrict__ x, const int* __restrict__ last_idx,
                       const float* __restrict__ W1, const float* __restrict__ b1,
                       const float* __restrict__ b2, float* __restrict__ A_pre) {
  __shared__ float Wl[128][132];
  __shared__ float vn[8][128];
  int t = threadIdx.x;
  for (int i = 0; i < 16; ++i) {
    int e = (t + i * 256) * 4;
    int r = e >> 7, c = e & 127;
    float4 v = *reinterpret_cast<const float4*>(W1 + e);
    Wl[r][c] = v.x; Wl[r][c + 1] = v.y; Wl[r][c + 2] = v.z; Wl[r][c + 3] = v.w;
  }
  int b0 = blockIdx.x * 8;
  for (int i = t; i < 8 * 128; i += 256) {
    int s = i >> 7, c = i & 127;
    vn[s][c] = x[(size_t)last_idx[b0 + s] * H + c];
  }
  __syncthreads();
  int h = t & 127, si = t >> 7;
  float bias = b1[h] + b2[h];
  for (int s = si; s < 8; s += 2) {
    float acc = bias;
    #pragma unroll
    for (int k = 0; k < 128; k += 4) {
      float4 w = *reinterpret_cast<const float4*>(&Wl[h][k]);
      acc += vn[s][k] * w.x + vn[s][k + 1] * w.y + vn[s][k + 2] * w.z + vn[s][k + 3] * w.w;
    }
    A_pre[(size_t)(b0 + s) * H + h] = acc;
  }
}

// ---------------------------------------------------------------- kernel 3
// Fused: z = A_pre[batch] + x@W2^T, alpha = sigmoid(z).Wq + bq,
// s_g[b] += alpha * x.
// K-split W2 staging (18KB LDS) -> 5 blocks/CU; A_pre rows staged to LDS
// (fast path cnt<=16); phase-2 x loads issued before the alpha barrier.
__global__ __launch_bounds__(256, 5)
void k_main(const float* __restrict__ x, const int* __restrict__ batch,
            const unsigned short* __restrict__ W2b, const float* __restrict__ Wq,
            const float* __restrict__ bq, const float* __restrict__ A_pre,
            float* __restrict__ s_g) {
  __shared__ unsigned short Wl[128][72];   // one K-half of W2 (144B row stride, 2-way max)
  __shared__ float apre_s[16][128];        // staged A_pre rows (fast path)
  __shared__ float alph[TILE];
  __shared__ int bsegs[TILE + 1];
  __shared__ float wqs[128];
  int t = threadIdx.x;
  int node0 = blockIdx.x * TILE;
  int w = t >> 6, lane = t & 63, r = lane & 15, ks = lane >> 4;
  int myrow = w * 16 + r;

  // ---- issue all global loads up front
  float4 af[8];
  const float* xrow = x + (size_t)(node0 + myrow) * H;
  #pragma unroll
  for (int k = 0; k < 4; ++k) {
    af[2 * k]     = *reinterpret_cast<const float4*>(xrow + k * 32 + ks * 8);
    af[2 * k + 1] = *reinterpret_cast<const float4*>(xrow + k * 32 + ks * 8 + 4);
  }
  bf16x8 w0[4], w1[4];                     // W2 K-halves, 8 chunks/row of 8 shorts
  #pragma unroll
  for (int i = 0; i < 4; ++i) {
    int u = t + i * 256, row = u >> 3, c = (u & 7) * 8;
    w0[i] = *reinterpret_cast<const bf16x8*>(W2b + row * 128 + c);
    w1[i] = *reinterpret_cast<const bf16x8*>(W2b + row * 128 + 64 + c);
  }
  int smin = batch[node0];
  int smax = batch[node0 + TILE - 1];
  int cnt = smax - smin + 1;
  bool fast = (cnt <= 16);
  if (fast) {                              // stage spanned A_pre rows (contiguous)
    const float4* src = reinterpret_cast<const float4*>(A_pre + ((size_t)smin << 7));
    float4* dst = reinterpret_cast<float4*>(&apre_s[0][0]);
    for (int i = t; i < cnt * 32; i += 256) dst[i] = src[i];
  }
  if (t <= TILE) {
    int idx = node0 + t;
    bsegs[t] = (idx < N_NODES) ? batch[idx] : -1;
  }
  if (t < 128) wqs[t] = Wq[t];
  // write W2 half0 to LDS
  #pragma unroll
  for (int i = 0; i < 4; ++i) {
    int u = t + i * 256, row = u >> 3, c = (u & 7) * 8;
    *reinterpret_cast<bf16x8*>(&Wl[row][c]) = w0[i];
  }
  // convert A-frags to bf16
  bf16x8 afr[4];
  #pragma unroll
  for (int k = 0; k < 4; ++k) {
    float4 lo = af[2 * k], hi = af[2 * k + 1];
    bf16x8 v;
    v[0] = bc(lo.x); v[1] = bc(lo.y); v[2] = bc(lo.z); v[3] = bc(lo.w);
    v[4] = bc(hi.x); v[5] = bc(hi.y); v[6] = bc(hi.z); v[7] = bc(hi.w);
    afr[k] = v;
  }
  __syncthreads();                         // Wl half0 + apre_s + bsegs ready

  f32x4 acc[8];
  #pragma unroll
  for (int nt = 0; nt < 8; ++nt) acc[nt] = (f32x4){0.f, 0.f, 0.f, 0.f};
  #pragma unroll
  for (int kg = 0; kg < 2; ++kg) {
    #pragma unroll
    for (int nt = 0; nt < 8; ++nt) {
      bf16x8 b = *reinterpret_cast<const bf16x8*>(&Wl[nt * 16 + r][kg * 32 + ks * 8]);
      acc[nt] = __builtin_amdgcn_mfma_f32_16x16x32_bf16(afr[kg], b, acc[nt], 0, 0, 0);
    }
  }
  __syncthreads();                         // half0 consumed
  #pragma unroll
  for (int i = 0; i < 4; ++i) {
    int u = t + i * 256, row = u >> 3, c = (u & 7) * 8;
    *reinterpret_cast<bf16x8*>(&Wl[row][c]) = w1[i];
  }
  __syncthreads();                         // half1 ready
  #pragma unroll
  for (int kg = 2; kg < 4; ++kg) {
    #pragma unroll
    for (int nt = 0; nt < 8; ++nt) {
      bf16x8 b = *reinterpret_cast<const bf16x8*>(&Wl[nt * 16 + r][(kg - 2) * 32 + ks * 8]);
      acc[nt] = __builtin_amdgcn_mfma_f32_16x16x32_bf16(afr[kg], b, acc[nt], 0, 0, 0);
    }
  }

  // ---- issue phase-2 x loads NOW so latency hides under alpha's exp chain
  int h = t & 127, grp = t >> 7;
  int base = grp * 32;
  const float* xp = x + (size_t)(node0 + base) * H + h;
  float xv[32];
  #pragma unroll
  for (int n = 0; n < 32; ++n) xv[n] = xp[(size_t)n * H];

  // ---- alpha: sigmoid + Wq-dot + 16-lane reduce
  float bqv = bq[0];
  float pa[4];
#define DO_ALPHA(GET) do {                                                   \
    _Pragma("unroll")                                                        \
    for (int j = 0; j < 4; ++j) {                                            \
      int row = bsegs[w * 16 + ks * 4 + j];                                  \
      float s = 0.f;                                                         \
      _Pragma("unroll")                                                      \
      for (int nt = 0; nt < 8; ++nt) {                                       \
        int col = nt * 16 + r;                                               \
        float z = acc[nt][j] + (GET);                                        \
        float g = 1.0f / (1.0f + __expf(-z));                                \
        s += g * wqs[col];                                                   \
      }                                                                      \
      s += __shfl_xor(s, 1); s += __shfl_xor(s, 2);                          \
      s += __shfl_xor(s, 4); s += __shfl_xor(s, 8);                          \
      pa[j] = s + bqv;                                                       \
    } } while (0)
  if (fast) DO_ALPHA(apre_s[row - smin][col]);
  else      DO_ALPHA(A_pre[(size_t)row * H + col]);
#undef DO_ALPHA
  if (r == 0) {
    #pragma unroll
    for (int j = 0; j < 4; ++j) alph[w * 16 + ks * 4 + j] = pa[j];
  }
  __syncthreads();                         // alph ready

  // ---- phase 2: s_g[b,h] += alpha_i * x[i,h]
  float accum = 0.f;
  #pragma unroll
  for (int n = 0; n < 32; ++n) {
    int ln = base + n;
    accum += alph[ln] * xv[n];
    if (bsegs[ln] != bsegs[ln + 1]) {
      atomicAdd(&s_g[(size_t)bsegs[ln] * H + h], accum);
      accum = 0.f;
    }
  }
  if (accum != 0.f) atomicAdd(&s_g[(size_t)bsegs[base + 31] * H + h], accum);
}

// ---------------------------------------------------------------- kernel 4
// s_h[b,h] = b3[h] + concat(v_n[b], s_g[b]) . W3[h,:]
__global__ void k_final(const float* __restrict__ x, const int* __restrict__ last_idx,
                        const float* __restrict__ s_g, const float* __restrict__ W3,
                        const float* __restrict__ b3, float* __restrict__ out) {
  __shared__ float Wl[128][132];
  __shared__ float vin[8][256];
  int t = threadIdx.x;
  int b0 = blockIdx.x * 8;
  for (int i = t; i < 8 * 256; i += 256) {
    int s = i >> 8, c = i & 255;
    float v;
    if (c < 128) v = x[(size_t)last_idx[b0 + s] * H + c];
    else         v = s_g[(size_t)(b0 + s) * H + (c - 128)];
    vin[s][c] = v;
  }
  int h = t & 127, si = t >> 7;
  float res[4];
  for (int half = 0; half < 2; ++half) {
    __syncthreads();
    for (int i = 0; i < 16; ++i) {
      int e = (t + i * 256) * 4;
      int r = e >> 7, c = e & 127;
      float4 v = *reinterpret_cast<const float4*>(W3 + (size_t)r * 256 + half * 128 + c);
      Wl[r][c] = v.x; Wl[r][c + 1] = v.y; Wl[r][c + 2] = v.z; Wl[r][c + 3] = v.w;
    }
    __syncthreads();
    #pragma unroll
    for (int sI = 0; sI < 4; ++sI) {
      int s = si + sI * 2;
      float acc = 0.f;
      #pragma unroll
      for (int k = 0; k < 128; k += 4) {
        float4 wv = *reinterpret_cast<const float4*>(&Wl[h][k]);
        acc += vin[s][half * 128 + k] * wv.x + vin[s][half * 128 + k + 1] * wv.y +
               vin[s][half * 128 + k + 2] * wv.z + vin[s][half * 128 + k + 3] * wv.w;
      }
      if (half == 0) res[sI] = acc;
      else out[(size_t)(b0 + s) * H + h] = res[sI] + acc + b3[h];
    }
  }
}

// ----------------------------------------------------------------
extern "C" void kernel_launch(void* const* d_in, const int* in_sizes, int n_in,
                              void* d_out, int out_size, void* d_ws, size_t ws_size,
                              hipStream_t stream) {
  const float* x     = (const float*)d_in[0];
  const int*   batch = (const int*)d_in[1];
  const float* W1    = (const float*)d_in[2];
  const float* b1    = (const float*)d_in[3];
  const float* W2    = (const float*)d_in[4];
  const float* b2    = (const float*)d_in[5];
  const float* Wq    = (const float*)d_in[6];
  const float* bq    = (const float*)d_in[7];
  const float* W3    = (const float*)d_in[8];
  const float* b3    = (const float*)d_in[9];
  float* out = (float*)d_out;

  char* ws = (char*)d_ws;
  int*            last_idx = (int*)ws;                                    // 16 KB
  float*          A_pre    = (float*)(ws + 16384);                        // 2 MB
  float*          s_g      = (float*)(ws + 16384 + 2097152);              // 2 MB
  unsigned short* W2b      = (unsigned short*)(ws + 16384 + 2 * 2097152); // 32 KB

  k_prep<<<N_NODES / 256, 256, 0, stream>>>(batch, last_idx, W2, W2b, s_g);
  k_apre<<<B_SESS / 8, 256, 0, stream>>>(x, last_idx, W1, b1, b2, A_pre);
  k_main<<<N_NODES / TILE, 256, 0, stream>>>(x, batch, W2b, Wq, bq, A_pre, s_g);
  k_final<<<B_SESS / 8, 256, 0, stream>>>(x, last_idx, s_g, W3, b3, out);
}